// Round 14
// baseline (331.220 us; speedup 1.0000x reference)
//
#include <hip/hip_runtime.h>
#include <hip/hip_bf16.h>
#include <stdint.h>

// Answer_Decoder: B=64, T=24, H=512, V=32000, E=256. All I/O float32.
// Attention is dead code (softmax over size-1 axis => ctx == cat(q,img)).
// Pipeline:
//   0) pack_w; build_x; G0 GEMM
//   1) fused_wave (256 blocks, 1/CU):
//      blocks 0..95  : LSTM (t,layer) wavefront, barrier-free per-wave cells.
//        W persistent in LDS (XOR swizzle); h slab layout; h stores sc1
//        (write-through to L3, no dirty L2); A reads normal cached;
//        flags [3][24][4 waves][32 blocks] -> per-BATCH-SLICE polling
//        (consumer wave w polls only wave-w producers: fan-in 128 -> 32).
//      blocks 96..255: fc workers. fcW n-panel persistent in LDS; h2 via
//        normal cached register-path loads; consume mt as layer-2 flags
//        appear; nt out stores.

typedef short bf16x8 __attribute__((ext_vector_type(8)));
typedef float f32x4 __attribute__((ext_vector_type(4)));

#define NLSTM 96
#define FCB   160
#define NTILE_N 250          // 32000/128
#define HSLOT 32768          // elems per (layer,t) h slot: 32 slabs * 64 * 16

__device__ __forceinline__ unsigned short f2b(float f) {
    uint32_t u = __builtin_bit_cast(uint32_t, f);
    uint32_t r = u + 0x7FFFu + ((u >> 16) & 1u);
    return (unsigned short)(r >> 16);
}
__device__ __forceinline__ float fsig(float x) {
    float e = __expf(-x);
    return __builtin_amdgcn_rcpf(1.0f + e);
}
__device__ __forceinline__ float ftanh(float x) {
    float e = __expf(-2.0f * x);
    return (1.0f - e) * __builtin_amdgcn_rcpf(1.0f + e);
}

// ---------------- pack recurrent weights (bf16, per-block contiguous) -------
__global__ __launch_bounds__(128) void pack_w(
    const float* __restrict__ Whh0,
    const float* __restrict__ Wih1, const float* __restrict__ Whh1,
    const float* __restrict__ Wih2, const float* __restrict__ Whh2,
    unsigned short* __restrict__ Wpk)
{
    int gid = blockIdx.x;                 // 3*32*64 = 6144
    int layer = gid / (32 * 64);
    int rem = gid % (32 * 64);
    int lbid = rem >> 6, r = rem & 63;
    int q = r >> 4, jj = r & 15;
    int grow = q * 512 + lbid * 16 + jj;
    int K = (layer == 0) ? 512 : 1024;
    size_t wbase = (layer == 0) ? 0
                 : (layer == 1) ? (size_t)32 * 64 * 512
                                : (size_t)32 * 64 * 512 + (size_t)32 * 64 * 1024;
    unsigned short* dst = Wpk + wbase + ((size_t)lbid * 64 + r) * K;
    const float *s0, *s1 = nullptr;
    if (layer == 0)      { s0 = Whh0 + (size_t)grow * 512; }
    else if (layer == 1) { s0 = Wih1 + (size_t)grow * 512; s1 = Whh1 + (size_t)grow * 512; }
    else                 { s0 = Wih2 + (size_t)grow * 512; s1 = Whh2 + (size_t)grow * 512; }
    {
        int k4 = threadIdx.x;
        f32x4 v = *(const f32x4*)&s0[k4 * 4];
        unsigned short o[4];
        #pragma unroll
        for (int j = 0; j < 4; ++j) o[j] = f2b(v[j]);
        *(uint64_t*)&dst[k4 * 4] = *(uint64_t*)o;
    }
    if (s1) {
        int k4 = threadIdx.x;
        f32x4 v = *(const f32x4*)&s1[k4 * 4];
        unsigned short o[4];
        #pragma unroll
        for (int j = 0; j < 4; ++j) o[j] = f2b(v[j]);
        *(uint64_t*)&dst[512 + k4 * 4] = *(uint64_t*)o;
    }
}

// ---------------- build X ----------------
__global__ __launch_bounds__(256) void build_x(
    const float* __restrict__ qf,
    const float* __restrict__ imf,
    const int* __restrict__ seq,
    const float* __restrict__ emb,
    unsigned short* __restrict__ X)
{
    int r = blockIdx.x;
    int t = r >> 6, b = r & 63;
    int tok = seq[b * 24 + t];
    for (int e = threadIdx.x; e < 1280; e += 256) {
        float v;
        if (e < 256)      v = emb[(size_t)tok * 256 + e];
        else if (e < 768) v = qf[b * 512 + (e - 256)];
        else              v = imf[b * 512 + (e - 768)];
        X[(size_t)r * 1280 + e] = f2b(v);
    }
}

// ---------------- 128x128 MFMA GEMM (G0): A bf16, W f32 (in-staging cvt) ----
__global__ __launch_bounds__(256) void gemm128(
    const unsigned short* __restrict__ A, int lda,
    const float* __restrict__ Wf, int ldb,
    int K,
    const float* __restrict__ bias0,
    const float* __restrict__ bias1,
    float* __restrict__ outf, int ldo, int mblocks, int xcdq)
{
    __shared__ unsigned short lA[128 * 72];
    __shared__ unsigned short lB[128 * 72];
    int lin = blockIdx.x;
    int wg = (lin & 7) * xcdq + (lin >> 3);
    const int m0 = (wg % mblocks) * 128, n0 = (wg / mblocks) * 128;
    const int tid = threadIdx.x;
    const int lane = tid & 63, wid = tid >> 6;
    const int wm = wid >> 1, wn = wid & 1;

    f32x4 acc[4][4] = {};

    for (int kt = 0; kt < K; kt += 64) {
        #pragma unroll
        for (int c = 0; c < 4; ++c) {
            int chunk = tid + c * 256;
            int row = chunk >> 3, kc = (chunk & 7) * 8;
            *(bf16x8*)&lA[row * 72 + kc] =
                *(const bf16x8*)&A[(size_t)(m0 + row) * lda + kt + kc];
            const float* bp = &Wf[(size_t)(n0 + row) * ldb + kt + kc];
            f32x4 v0 = *(const f32x4*)bp;
            f32x4 v1 = *(const f32x4*)(bp + 4);
            unsigned short o[8];
            #pragma unroll
            for (int x = 0; x < 4; ++x) { o[x] = f2b(v0[x]); o[4 + x] = f2b(v1[x]); }
            *(bf16x8*)&lB[row * 72 + kc] = *(bf16x8*)o;
        }
        __syncthreads();
        #pragma unroll
        for (int ks = 0; ks < 64; ks += 32) {
            int kl = ks + ((lane >> 4) << 3);
            bf16x8 af[4], bfr[4];
            #pragma unroll
            for (int i = 0; i < 4; ++i)
                af[i] = *(const bf16x8*)&lA[(wm * 64 + i * 16 + (lane & 15)) * 72 + kl];
            #pragma unroll
            for (int j = 0; j < 4; ++j)
                bfr[j] = *(const bf16x8*)&lB[(wn * 64 + j * 16 + (lane & 15)) * 72 + kl];
            #pragma unroll
            for (int i = 0; i < 4; ++i)
                #pragma unroll
                for (int j = 0; j < 4; ++j)
                    acc[i][j] = __builtin_amdgcn_mfma_f32_16x16x32_bf16(
                        af[i], bfr[j], acc[i][j], 0, 0, 0);
        }
        __syncthreads();
    }

    #pragma unroll
    for (int i = 0; i < 4; ++i) {
        #pragma unroll
        for (int j = 0; j < 4; ++j) {
            int n = n0 + wn * 64 + j * 16 + (lane & 15);
            float bias = bias0[n] + bias1[n];
            #pragma unroll
            for (int r = 0; r < 4; ++r) {
                int m = m0 + wm * 64 + i * 16 + ((lane >> 4) << 2) + r;
                outf[(size_t)m * ldo + n] = acc[i][j][r] + bias;
            }
        }
    }
}

// ---- lstm primitives: A reads NORMAL CACHED; h in slab layout ----
#define ISSUE_CHUNK(buf, kb0)                                                 \
    {                                                                         \
        _Pragma("unroll")                                                     \
        for (int u_ = 0; u_ < 8; ++u_) {                                      \
            int kg_ = (kb0) + u_ * 32 + lk;                                   \
            const unsigned short* hb_ = (kg_ < 512) ? A0 : A1;                \
            int kk_ = kg_ & 511;                                              \
            const unsigned short* ap_ =                                       \
                hb_ + ((kk_ >> 4) << 10) + brow16 + (kk_ & 15);               \
            asm volatile("global_load_dwordx4 %0, %1, off"                    \
                         : "=v"(buf[u_]) : "v"(ap_) : "memory");              \
        }                                                                     \
    }
#define MFMA_CHUNK(buf, kb0)                                                  \
    {                                                                         \
        _Pragma("unroll")                                                     \
        for (int u_ = 0; u_ < 8; ++u_) {                                      \
            int ksl_ = (kb0) + u_ * 32 + lk;                                  \
            _Pragma("unroll")                                                 \
            for (int q_ = 0; q_ < 4; ++q_) {                                  \
                int gx_ = ((ksl_ >> 3) ^ (lrow & 7)) << 3;                    \
                bf16x8 bq_ = *(const bf16x8*)&lb[(q_ * 16 + lrow) * K + gx_]; \
                acc[q_] = __builtin_amdgcn_mfma_f32_16x16x32_bf16(            \
                    buf[u_], bq_, acc[q_], 0, 0, 0);                          \
            }                                                                 \
        }                                                                     \
    }
#define VM_WAIT(n) { asm volatile("s_waitcnt vmcnt(" #n ")" ::: "memory");    \
                     __builtin_amdgcn_sched_barrier(0); }
// poll 32 contiguous per-wave flags (batch-slice fan-in = 32)
#define POLL32(fbase)                                                         \
    {                                                                         \
        const unsigned int* fp_ = (fbase);                                    \
        int idx_ = lane & 31;                                                 \
        while (true) {                                                        \
            unsigned v_ = __hip_atomic_load((unsigned int*)&fp_[idx_],        \
                                            __ATOMIC_RELAXED,                 \
                                            __HIP_MEMORY_SCOPE_AGENT);       \
            if (__all(v_ != 0u)) break;                                       \
            __builtin_amdgcn_s_sleep(1);                                      \
        }                                                                     \
    }

// ---- fc: register-path A, NORMAL cached loads ----
#define FC_ISSUE_G(buf, ks0)                                                  \
    {                                                                         \
        _Pragma("unroll")                                                     \
        for (int u_ = 0; u_ < 4; ++u_) {                                      \
            _Pragma("unroll")                                                 \
            for (int i_ = 0; i_ < 4; ++i_) {                                  \
                int rl_ = i_ * 16 + lrow;                                     \
                int k_ = (ks0) + u_ * 32 + lk;                                \
                const unsigned short* ap_ = h2                                \
                    + (size_t)(2 * mt + wm + 1) * HSLOT                       \
                    + ((k_ >> 4) << 10) + (rl_ << 4) + (k_ & 15);             \
                asm volatile("global_load_dwordx4 %0, %1, off"                \
                             : "=v"(buf[u_ * 4 + i_]) : "v"(ap_) : "memory"); \
            }                                                                 \
        }                                                                     \
    }
#define FC_MFMA_G(buf, ks0)                                                   \
    {                                                                         \
        _Pragma("unroll")                                                     \
        for (int u_ = 0; u_ < 4; ++u_) {                                      \
            int ks_ = (ks0) + u_ * 32 + lk;                                   \
            _Pragma("unroll")                                                 \
            for (int jj_ = 0; jj_ < 4; ++jj_) {                               \
                int row_ = wn * 64 + jj_ * 16 + lrow;                         \
                int gx_ = ((ks_ >> 3) ^ (row_ & 7)) << 3;                     \
                bf16x8 bq_ = *(const bf16x8*)&lB[row_ * 512 + gx_];           \
                _Pragma("unroll")                                             \
                for (int i_ = 0; i_ < 4; ++i_)                                \
                    acc[i_][jj_] = __builtin_amdgcn_mfma_f32_16x16x32_bf16(   \
                        buf[u_ * 4 + i_], bq_, acc[i_][jj_], 0, 0, 0);        \
            }                                                                 \
        }                                                                     \
    }

// ---------------- fused persistent kernel ----------------
// flags layout: [3][24][4 waves][32 blocks] u32
__global__ __launch_bounds__(256, 1) void fused_wave(
    const unsigned short* __restrict__ Wpk,
    const float* __restrict__ G0,            // [24][64][2048]
    const float* __restrict__ bih1, const float* __restrict__ bhh1,
    const float* __restrict__ bih2, const float* __restrict__ bhh2,
    unsigned short* __restrict__ hst,        // [3][25][HSLOT] slab layout
    unsigned int* __restrict__ flags,        // [3][24][128]
    const float* __restrict__ fcW,           // [32000][512] f32
    const float* __restrict__ fcb,
    float* __restrict__ out)                 // [64][24][32000]
{
    extern __shared__ char smem[];
    const int bid = blockIdx.x;
    const int tid = threadIdx.x;
    const int lane = tid & 63, w = tid >> 6;
    const int lrow = lane & 15, lk = (lane >> 4) * 8;

    if (bid < NLSTM) {
        // ================= LSTM wavefront =================
        unsigned short* lb = (unsigned short*)smem;   // [64][K], XOR-swizzled
        const int layer = bid >> 5;
        const int lbid = bid & 31;
        const int j0 = lbid * 16;

        const int K = (layer == 0) ? 512 : 1024;
        const size_t wbase = (layer == 0) ? 0
                           : (layer == 1) ? (size_t)32 * 64 * 512
                                          : (size_t)32 * 64 * 512 + (size_t)32 * 64 * 1024;
        const unsigned short* Wblk = Wpk + wbase + (size_t)lbid * 64 * K;

        {   // stage W once, granule-XOR swizzle
            const int kshift = (layer == 0) ? 6 : 7;
            const int gm = (K >> 3) - 1;
            const int total = 64 << kshift;
            for (int idx = tid; idx < total; idx += 256) {
                int row = idx >> kshift, g = idx & gm;
                int gx = g ^ (row & 7);
                *(bf16x8*)&lb[row * K + gx * 8] =
                    *(const bf16x8*)&Wblk[(size_t)row * K + g * 8];
            }
        }
        __syncthreads();   // the only block barrier

        unsigned short* hl = hst + (size_t)layer * 25 * HSLOT;
        const unsigned short* hlow =
            (layer > 0) ? hst + (size_t)(layer - 1) * 25 * HSLOT : nullptr;

        float pb[4] = {0.f, 0.f, 0.f, 0.f};
        if (layer == 1) {
            #pragma unroll
            for (int q = 0; q < 4; ++q)
                pb[q] = bih1[q * 512 + j0 + lrow] + bhh1[q * 512 + j0 + lrow];
        } else if (layer == 2) {
            #pragma unroll
            for (int q = 0; q < 4; ++q)
                pb[q] = bih2[q * 512 + j0 + lrow] + bhh2[q * 512 + j0 + lrow];
        }

        float creg[4] = {0.f, 0.f, 0.f, 0.f};
        const int brow16 = (w * 16 + lrow) << 4;

        for (int t = 0; t < 24; ++t) {
            // G0 prefetch (static, overlaps polls)
            float g0p[16];
            if (layer == 0) {
                const float* gp = G0 + (size_t)t * 64 * 2048;
                #pragma unroll
                for (int r = 0; r < 4; ++r) {
                    int b = w * 16 + ((lane >> 4) << 2) + r;
                    #pragma unroll
                    for (int q = 0; q < 4; ++q)
                        g0p[r * 4 + q] = gp[(size_t)b * 2048 + q * 512 + j0 + lrow];
                }
            }

            const unsigned short* A0 = (layer == 0)
                ? hl + (size_t)t * HSLOT
                : hlow + (size_t)(t + 1) * HSLOT;
            const unsigned short* A1 = (layer == 0)
                ? A0
                : hl + (size_t)t * HSLOT;

            f32x4 acc[4] = {};
            bf16x8 bufA[8], bufB[8], bufC[8], bufD[8];

            if (layer == 0) {
                if (t > 0) POLL32(flags + (t - 1) * 128 + w * 32);
                ISSUE_CHUNK(bufA, 0); ISSUE_CHUNK(bufB, 256);
                VM_WAIT(8); MFMA_CHUNK(bufA, 0);
                VM_WAIT(0); MFMA_CHUNK(bufB, 256);
            } else {
                // own-layer slice first (A1 = h[l][t-1] rows w*16..): issue early
                if (t > 0) POLL32(flags + (layer * 24 + t - 1) * 128 + w * 32);
                ISSUE_CHUNK(bufC, 512); ISSUE_CHUNK(bufD, 768);
                // lower layer slice (A0 = h[l-1][t] rows w*16..)
                POLL32(flags + ((layer - 1) * 24 + t) * 128 + w * 32);
                ISSUE_CHUNK(bufA, 0); ISSUE_CHUNK(bufB, 256);
                VM_WAIT(24); MFMA_CHUNK(bufC, 512);
                VM_WAIT(16); MFMA_CHUNK(bufD, 768);
                VM_WAIT(8);  MFMA_CHUNK(bufA, 0);
                VM_WAIT(0);  MFMA_CHUNK(bufB, 256);
            }

            // epilogue; h stores: full-line slab writes, sc1 write-through
            unsigned short* hslot = hl + (size_t)(t + 1) * HSLOT + (lbid << 10);
            #pragma unroll
            for (int r = 0; r < 4; ++r) {
                int b = w * 16 + ((lane >> 4) << 2) + r;
                float g[4];
                #pragma unroll
                for (int q = 0; q < 4; ++q) {
                    float p = (layer == 0) ? g0p[r * 4 + q] : pb[q];
                    g[q] = acc[q][r] + p;
                }
                float ig = fsig(g[0]);
                float fg = fsig(g[1]);
                float gg = ftanh(g[2]);
                float og = fsig(g[3]);
                float cn = fg * creg[r] + ig * gg;
                creg[r] = cn;
                float h = og * ftanh(cn);
                unsigned int hb = (unsigned int)f2b(h);
                unsigned short* hp = hslot + (b << 4) + lrow;
                asm volatile("global_store_short %0, %1, off sc1"
                             :: "v"(hp), "v"(hb) : "memory");
            }
            asm volatile("s_waitcnt vmcnt(0)" ::: "memory");
            if (lane == 0) {
                __hip_atomic_store(&flags[(layer * 24 + t) * 128 + w * 32 + lbid], 1u,
                                   __ATOMIC_RELAXED, __HIP_MEMORY_SCOPE_AGENT);
            }
        }
    } else {
        // ================= fc consumers: LDS panel, cached A ==============
        unsigned short* lB = (unsigned short*)smem;    // [128][512] bf16 swz
        const int f = bid - NLSTM;
        const int wm = w >> 1, wn = w & 1;
        const unsigned short* h2 = hst + (size_t)2 * 25 * HSLOT;

        for (int p = 0; p < 2; ++p) {
            int ntp = f + p * FCB;
            if (ntp >= NTILE_N) break;
            int n0 = ntp * 128;
            __syncthreads();   // prior panel's LDS reads done before overwrite
            for (int idx = tid; idx < 128 * 64; idx += 256) {
                int row = idx >> 6, g = idx & 63;
                const float* bp = &fcW[(size_t)(n0 + row) * 512 + g * 8];
                f32x4 v0 = *(const f32x4*)bp;
                f32x4 v1 = *(const f32x4*)(bp + 4);
                unsigned short o[8];
                #pragma unroll
                for (int x = 0; x < 4; ++x) { o[x] = f2b(v0[x]); o[4 + x] = f2b(v1[x]); }
                *(bf16x8*)&lB[row * 512 + ((g ^ (row & 7)) << 3)] = *(bf16x8*)o;
            }
            __syncthreads();

            for (int mt = 0; mt < 12; ++mt) {
                // wait for layer-2 flags of t=2mt, 2mt+1 (256 words)
                if (tid < 64) {
                    const unsigned int* fb = flags + (2 * 24 + 2 * mt) * 128;
                    while (true) {
                        unsigned ok = 1u;
                        #pragma unroll
                        for (int s = 0; s < 4; ++s)
                            ok &= (__hip_atomic_load((unsigned int*)&fb[s * 64 + lane],
                                                     __ATOMIC_RELAXED,
                                                     __HIP_MEMORY_SCOPE_AGENT) != 0u);
                        if (__all(ok)) break;
                        __builtin_amdgcn_s_sleep(16);
                    }
                }
                __syncthreads();

                f32x4 acc[4][4] = {};
                bf16x8 gA[16], gB[16];
                FC_ISSUE_G(gA, 0); FC_ISSUE_G(gB, 128);
                VM_WAIT(16); FC_MFMA_G(gA, 0);
                FC_ISSUE_G(gA, 256);
                VM_WAIT(16); FC_MFMA_G(gB, 128);
                FC_ISSUE_G(gB, 384);
                VM_WAIT(16); FC_MFMA_G(gA, 256);
                VM_WAIT(0);  FC_MFMA_G(gB, 384);

                const int m0 = mt * 128;
                #pragma unroll
                for (int i = 0; i < 4; ++i) {
                    #pragma unroll
                    for (int jj = 0; jj < 4; ++jj) {
                        int n = n0 + wn * 64 + jj * 16 + lrow;
                        float bias = fcb[n];
                        #pragma unroll
                        for (int r = 0; r < 4; ++r) {
                            int m = m0 + wm * 64 + i * 16 + ((lane >> 4) << 2) + r;
                            int b = m & 63, t = m >> 6;
                            __builtin_nontemporal_store(
                                acc[i][jj][r] + bias,
                                &out[(size_t)(b * 24 + t) * 32000 + n]);
                        }
                    }
                }
            }
        }
    }
}

// ---------------- launch ----------------
extern "C" void kernel_launch(void* const* d_in, const int* in_sizes, int n_in,
                              void* d_out, int out_size, void* d_ws, size_t ws_size,
                              hipStream_t stream) {
    const float* qf  = (const float*)d_in[0];
    const float* imf = (const float*)d_in[1];
    const int*   seq = (const int*)d_in[2];
    const float* emb = (const float*)d_in[3];
    // d_in[4..6] dead code
    const float* fcW = (const float*)d_in[7];
    const float* fcb = (const float*)d_in[8];
    const float* Wih[3] = {(const float*)d_in[9],  (const float*)d_in[13], (const float*)d_in[17]};
    const float* Whh[3] = {(const float*)d_in[10], (const float*)d_in[14], (const float*)d_in[18]};
    const float* bih[3] = {(const float*)d_in[11], (const float*)d_in[15], (const float*)d_in[19]};
    const float* bhh[3] = {(const float*)d_in[12], (const float*)d_in[16], (const float*)d_in[20]};

    char* ws = (char*)d_ws;
    unsigned short* X     = (unsigned short*)(ws + 0);          // 3,932,160
    float*          G0    = (float*)(ws + 3932160);             // 12,582,912
    unsigned short* hst   = (unsigned short*)(ws + 16515072);   // 4,915,200
    unsigned int*   flags = (unsigned int*)(ws + 21430272);     // 36,864
    unsigned short* Wpk   = (unsigned short*)(ws + 21467136);   // 10,485,760

    hipMemsetAsync(flags, 0, 36864, stream);
    for (int l = 0; l < 3; ++l)
        hipMemsetAsync(hst + (size_t)l * 25 * HSLOT, 0, HSLOT * 2, stream);

    pack_w<<<3 * 32 * 64, 128, 0, stream>>>(Whh[0], Wih[1], Whh[1], Wih[2], Whh[2], Wpk);
    build_x<<<1536, 256, 0, stream>>>(qf, imf, seq, emb, X);

    // G0 = X @ W_ih0^T + b_ih0 + b_hh0
    gemm128<<<192, 256, 0, stream>>>(
        X, 1280, Wih[0], 1280, 1280, bih[0], bhh[0], G0, 2048, 12, 192 / 8);

    // fused: 96 lstm + 160 fc blocks, 128 KiB dynamic LDS (1 block/CU)
    fused_wave<<<NLSTM + FCB, 256, 131072, stream>>>(
        Wpk, G0, bih[1], bhh[1], bih[2], bhh[2], hst, flags,
        fcW, fcb, (float*)d_out);
}

// Round 15
// 299.575 us; speedup vs baseline: 1.1056x; 1.1056x over previous
//
#include <hip/hip_runtime.h>
#include <hip/hip_bf16.h>
#include <stdint.h>

// Answer_Decoder: B=64, T=24, H=512, V=32000, E=256. All I/O float32.
// Attention is dead code (softmax over size-1 axis => ctx == cat(q,img)).
// Pipeline (4 dispatches):
//   0) prep: pack_w + build_x + zero(flags, h slot0)  [one kernel]
//   1) gemm128: G0 = X @ W_ih0^T + b_ih0 + b_hh0
//   2) lstm_wave (96 blocks): (t,layer) wavefront, barrier-free per-wave
//      cells; W persistent in LDS (XOR swizzle); h slab layout; h stores
//      sc1 write-through; A reads normal cached; per-wave flags with
//      BATCH-SLICE polling (fan-in 32).
//   3) fc_gemm (250 blocks): fcW panel persistent in LDS; store-drain
//      decoupled from next tile's loads (loads issued before stores,
//      vmcnt(63) tile entry); nt out stores.

typedef short bf16x8 __attribute__((ext_vector_type(8)));
typedef float f32x4 __attribute__((ext_vector_type(4)));

#define NLSTM 96
#define NTILE_N 250          // 32000/128
#define HSLOT 32768          // elems per (layer,t) h slot: 32 slabs * 64 * 16

__device__ __forceinline__ unsigned short f2b(float f) {
    uint32_t u = __builtin_bit_cast(uint32_t, f);
    uint32_t r = u + 0x7FFFu + ((u >> 16) & 1u);
    return (unsigned short)(r >> 16);
}
__device__ __forceinline__ float fsig(float x) {
    float e = __expf(-x);
    return __builtin_amdgcn_rcpf(1.0f + e);
}
__device__ __forceinline__ float ftanh(float x) {
    float e = __expf(-2.0f * x);
    return (1.0f - e) * __builtin_amdgcn_rcpf(1.0f + e);
}

// ---------------- prep: pack_w + build_x + zeroing, one dispatch ----------
// blocks 0..6143: pack_w (one (layer,lbid,row) each)
// blocks 6144..7679: build_x rows
// blocks 7680..7687: zero flags + h slot0 of each layer
__global__ __launch_bounds__(256) void prep(
    const float* __restrict__ Whh0,
    const float* __restrict__ Wih1, const float* __restrict__ Whh1,
    const float* __restrict__ Wih2, const float* __restrict__ Whh2,
    unsigned short* __restrict__ Wpk,
    const float* __restrict__ qf,
    const float* __restrict__ imf,
    const int* __restrict__ seq,
    const float* __restrict__ emb,
    unsigned short* __restrict__ X,
    unsigned int* __restrict__ flags,     // 9216 u32
    unsigned short* __restrict__ hst)
{
    int gid = blockIdx.x;
    int tid = threadIdx.x;
    if (gid < 6144) {
        int layer = gid / (32 * 64);
        int rem = gid % (32 * 64);
        int lbid = rem >> 6, r = rem & 63;
        int q = r >> 4, jj = r & 15;
        int grow = q * 512 + lbid * 16 + jj;
        int K = (layer == 0) ? 512 : 1024;
        size_t wbase = (layer == 0) ? 0
                     : (layer == 1) ? (size_t)32 * 64 * 512
                                    : (size_t)32 * 64 * 512 + (size_t)32 * 64 * 1024;
        unsigned short* dst = Wpk + wbase + ((size_t)lbid * 64 + r) * K;
        const float *s0, *s1 = nullptr;
        if (layer == 0)      { s0 = Whh0 + (size_t)grow * 512; }
        else if (layer == 1) { s0 = Wih1 + (size_t)grow * 512; s1 = Whh1 + (size_t)grow * 512; }
        else                 { s0 = Wih2 + (size_t)grow * 512; s1 = Whh2 + (size_t)grow * 512; }
        int half = tid >> 7, k4 = tid & 127;       // 128 threads per half
        const float* src = (half == 0) ? s0 : s1;
        if (src) {
            f32x4 v = *(const f32x4*)&src[k4 * 4];
            unsigned short o[4];
            #pragma unroll
            for (int j = 0; j < 4; ++j) o[j] = f2b(v[j]);
            *(uint64_t*)&dst[half * 512 + k4 * 4] = *(uint64_t*)o;
        }
    } else if (gid < 7680) {
        int r = gid - 6144;
        int t = r >> 6, b = r & 63;
        int tok = seq[b * 24 + t];
        for (int e = tid; e < 1280; e += 256) {
            float v;
            if (e < 256)      v = emb[(size_t)tok * 256 + e];
            else if (e < 768) v = qf[b * 512 + (e - 256)];
            else              v = imf[b * 512 + (e - 768)];
            X[(size_t)r * 1280 + e] = f2b(v);
        }
    } else {
        int z = (gid - 7680) * 256 + tid;          // 8 blocks * 256 = 2048 workers
        // flags: 9216 u32
        for (int i = z; i < 9216; i += 2048) flags[i] = 0u;
        // h slot0 per layer: 3 * HSLOT u16 = 3 * 16384 u32
        unsigned int* h32 = (unsigned int*)hst;
        for (int l = 0; l < 3; ++l) {
            unsigned int* base = h32 + (size_t)l * 25 * (HSLOT / 2);
            for (int i = z; i < HSLOT / 2; i += 2048) base[i] = 0u;
        }
    }
}

// ---------------- 128x128 MFMA GEMM (G0): A bf16, W f32 (in-staging cvt) ----
__global__ __launch_bounds__(256) void gemm128(
    const unsigned short* __restrict__ A, int lda,
    const float* __restrict__ Wf, int ldb,
    int K,
    const float* __restrict__ bias0,
    const float* __restrict__ bias1,
    float* __restrict__ outf, int ldo, int mblocks, int xcdq)
{
    __shared__ unsigned short lA[128 * 72];
    __shared__ unsigned short lB[128 * 72];
    int lin = blockIdx.x;
    int wg = (lin & 7) * xcdq + (lin >> 3);
    const int m0 = (wg % mblocks) * 128, n0 = (wg / mblocks) * 128;
    const int tid = threadIdx.x;
    const int lane = tid & 63, wid = tid >> 6;
    const int wm = wid >> 1, wn = wid & 1;

    f32x4 acc[4][4] = {};

    for (int kt = 0; kt < K; kt += 64) {
        #pragma unroll
        for (int c = 0; c < 4; ++c) {
            int chunk = tid + c * 256;
            int row = chunk >> 3, kc = (chunk & 7) * 8;
            *(bf16x8*)&lA[row * 72 + kc] =
                *(const bf16x8*)&A[(size_t)(m0 + row) * lda + kt + kc];
            const float* bp = &Wf[(size_t)(n0 + row) * ldb + kt + kc];
            f32x4 v0 = *(const f32x4*)bp;
            f32x4 v1 = *(const f32x4*)(bp + 4);
            unsigned short o[8];
            #pragma unroll
            for (int x = 0; x < 4; ++x) { o[x] = f2b(v0[x]); o[4 + x] = f2b(v1[x]); }
            *(bf16x8*)&lB[row * 72 + kc] = *(bf16x8*)o;
        }
        __syncthreads();
        #pragma unroll
        for (int ks = 0; ks < 64; ks += 32) {
            int kl = ks + ((lane >> 4) << 3);
            bf16x8 af[4], bfr[4];
            #pragma unroll
            for (int i = 0; i < 4; ++i)
                af[i] = *(const bf16x8*)&lA[(wm * 64 + i * 16 + (lane & 15)) * 72 + kl];
            #pragma unroll
            for (int j = 0; j < 4; ++j)
                bfr[j] = *(const bf16x8*)&lB[(wn * 64 + j * 16 + (lane & 15)) * 72 + kl];
            #pragma unroll
            for (int i = 0; i < 4; ++i)
                #pragma unroll
                for (int j = 0; j < 4; ++j)
                    acc[i][j] = __builtin_amdgcn_mfma_f32_16x16x32_bf16(
                        af[i], bfr[j], acc[i][j], 0, 0, 0);
        }
        __syncthreads();
    }

    #pragma unroll
    for (int i = 0; i < 4; ++i) {
        #pragma unroll
        for (int j = 0; j < 4; ++j) {
            int n = n0 + wn * 64 + j * 16 + (lane & 15);
            float bias = bias0[n] + bias1[n];
            #pragma unroll
            for (int r = 0; r < 4; ++r) {
                int m = m0 + wm * 64 + i * 16 + ((lane >> 4) << 2) + r;
                outf[(size_t)m * ldo + n] = acc[i][j][r] + bias;
            }
        }
    }
}

// ---- lstm primitives: A reads NORMAL CACHED; h in slab layout ----
#define ISSUE_CHUNK(buf, kb0)                                                 \
    {                                                                         \
        _Pragma("unroll")                                                     \
        for (int u_ = 0; u_ < 8; ++u_) {                                      \
            int kg_ = (kb0) + u_ * 32 + lk;                                   \
            const unsigned short* hb_ = (kg_ < 512) ? A0 : A1;                \
            int kk_ = kg_ & 511;                                              \
            const unsigned short* ap_ =                                       \
                hb_ + ((kk_ >> 4) << 10) + brow16 + (kk_ & 15);               \
            asm volatile("global_load_dwordx4 %0, %1, off"                    \
                         : "=v"(buf[u_]) : "v"(ap_) : "memory");              \
        }                                                                     \
    }
#define MFMA_CHUNK(buf, kb0)                                                  \
    {                                                                         \
        _Pragma("unroll")                                                     \
        for (int u_ = 0; u_ < 8; ++u_) {                                      \
            int ksl_ = (kb0) + u_ * 32 + lk;                                  \
            _Pragma("unroll")                                                 \
            for (int q_ = 0; q_ < 4; ++q_) {                                  \
                int gx_ = ((ksl_ >> 3) ^ (lrow & 7)) << 3;                    \
                bf16x8 bq_ = *(const bf16x8*)&lb[(q_ * 16 + lrow) * K + gx_]; \
                acc[q_] = __builtin_amdgcn_mfma_f32_16x16x32_bf16(            \
                    buf[u_], bq_, acc[q_], 0, 0, 0);                          \
            }                                                                 \
        }                                                                     \
    }
#define VM_WAIT(n) { asm volatile("s_waitcnt vmcnt(" #n ")" ::: "memory");    \
                     __builtin_amdgcn_sched_barrier(0); }
// poll 32 contiguous per-wave flags (batch-slice fan-in = 32)
#define POLL32(fbase)                                                         \
    {                                                                         \
        const unsigned int* fp_ = (fbase);                                    \
        int idx_ = lane & 31;                                                 \
        while (true) {                                                        \
            unsigned v_ = __hip_atomic_load((unsigned int*)&fp_[idx_],        \
                                            __ATOMIC_RELAXED,                 \
                                            __HIP_MEMORY_SCOPE_AGENT);       \
            if (__all(v_ != 0u)) break;                                       \
            __builtin_amdgcn_s_sleep(1);                                      \
        }                                                                     \
    }

// ---------------- persistent wavefront LSTM (96 blocks) ----------------
// flags layout: [3][24][4 waves][32 blocks] u32
__global__ __launch_bounds__(256, 1) void lstm_wave(
    const unsigned short* __restrict__ Wpk,
    const float* __restrict__ G0,            // [24][64][2048]
    const float* __restrict__ bih1, const float* __restrict__ bhh1,
    const float* __restrict__ bih2, const float* __restrict__ bhh2,
    unsigned short* __restrict__ hst,        // [3][25][HSLOT] slab layout
    unsigned int* __restrict__ flags)        // [3][24][128]
{
    extern __shared__ char smem[];
    unsigned short* lb = (unsigned short*)smem;   // [64][K], XOR-swizzled
    const int bid = blockIdx.x;
    const int tid = threadIdx.x;
    const int lane = tid & 63, w = tid >> 6;
    const int lrow = lane & 15, lk = (lane >> 4) * 8;
    const int layer = bid >> 5;
    const int lbid = bid & 31;
    const int j0 = lbid * 16;

    const int K = (layer == 0) ? 512 : 1024;
    const size_t wbase = (layer == 0) ? 0
                       : (layer == 1) ? (size_t)32 * 64 * 512
                                      : (size_t)32 * 64 * 512 + (size_t)32 * 64 * 1024;
    const unsigned short* Wblk = Wpk + wbase + (size_t)lbid * 64 * K;

    {   // stage W once, granule-XOR swizzle
        const int kshift = (layer == 0) ? 6 : 7;
        const int gm = (K >> 3) - 1;
        const int total = 64 << kshift;
        for (int idx = tid; idx < total; idx += 256) {
            int row = idx >> kshift, g = idx & gm;
            int gx = g ^ (row & 7);
            *(bf16x8*)&lb[row * K + gx * 8] =
                *(const bf16x8*)&Wblk[(size_t)row * K + g * 8];
        }
    }
    __syncthreads();   // the only block barrier

    unsigned short* hl = hst + (size_t)layer * 25 * HSLOT;
    const unsigned short* hlow =
        (layer > 0) ? hst + (size_t)(layer - 1) * 25 * HSLOT : nullptr;

    float pb[4] = {0.f, 0.f, 0.f, 0.f};
    if (layer == 1) {
        #pragma unroll
        for (int q = 0; q < 4; ++q)
            pb[q] = bih1[q * 512 + j0 + lrow] + bhh1[q * 512 + j0 + lrow];
    } else if (layer == 2) {
        #pragma unroll
        for (int q = 0; q < 4; ++q)
            pb[q] = bih2[q * 512 + j0 + lrow] + bhh2[q * 512 + j0 + lrow];
    }

    float creg[4] = {0.f, 0.f, 0.f, 0.f};
    const int brow16 = (w * 16 + lrow) << 4;

    for (int t = 0; t < 24; ++t) {
        // G0 prefetch (static, overlaps polls)
        float g0p[16];
        if (layer == 0) {
            const float* gp = G0 + (size_t)t * 64 * 2048;
            #pragma unroll
            for (int r = 0; r < 4; ++r) {
                int b = w * 16 + ((lane >> 4) << 2) + r;
                #pragma unroll
                for (int q = 0; q < 4; ++q)
                    g0p[r * 4 + q] = gp[(size_t)b * 2048 + q * 512 + j0 + lrow];
            }
        }

        const unsigned short* A0 = (layer == 0)
            ? hl + (size_t)t * HSLOT
            : hlow + (size_t)(t + 1) * HSLOT;
        const unsigned short* A1 = (layer == 0)
            ? A0
            : hl + (size_t)t * HSLOT;

        f32x4 acc[4] = {};
        bf16x8 bufA[8], bufB[8], bufC[8], bufD[8];

        if (layer == 0) {
            if (t > 0) POLL32(flags + (t - 1) * 128 + w * 32);
            ISSUE_CHUNK(bufA, 0); ISSUE_CHUNK(bufB, 256);
            VM_WAIT(8); MFMA_CHUNK(bufA, 0);
            VM_WAIT(0); MFMA_CHUNK(bufB, 256);
        } else {
            // own-layer slice first (A1 = h[l][t-1] rows w*16..): issue early
            if (t > 0) POLL32(flags + (layer * 24 + t - 1) * 128 + w * 32);
            ISSUE_CHUNK(bufC, 512); ISSUE_CHUNK(bufD, 768);
            // lower layer slice (A0 = h[l-1][t] rows w*16..)
            POLL32(flags + ((layer - 1) * 24 + t) * 128 + w * 32);
            ISSUE_CHUNK(bufA, 0); ISSUE_CHUNK(bufB, 256);
            VM_WAIT(24); MFMA_CHUNK(bufC, 512);
            VM_WAIT(16); MFMA_CHUNK(bufD, 768);
            VM_WAIT(8);  MFMA_CHUNK(bufA, 0);
            VM_WAIT(0);  MFMA_CHUNK(bufB, 256);
        }

        // epilogue; h stores: full-line slab writes, sc1 write-through
        unsigned short* hslot = hl + (size_t)(t + 1) * HSLOT + (lbid << 10);
        #pragma unroll
        for (int r = 0; r < 4; ++r) {
            int b = w * 16 + ((lane >> 4) << 2) + r;
            float g[4];
            #pragma unroll
            for (int q = 0; q < 4; ++q) {
                float p = (layer == 0) ? g0p[r * 4 + q] : pb[q];
                g[q] = acc[q][r] + p;
            }
            float ig = fsig(g[0]);
            float fg = fsig(g[1]);
            float gg = ftanh(g[2]);
            float og = fsig(g[3]);
            float cn = fg * creg[r] + ig * gg;
            creg[r] = cn;
            float h = og * ftanh(cn);
            unsigned int hb = (unsigned int)f2b(h);
            unsigned short* hp = hslot + (b << 4) + lrow;
            asm volatile("global_store_short %0, %1, off sc1"
                         :: "v"(hp), "v"(hb) : "memory");
        }
        asm volatile("s_waitcnt vmcnt(0)" ::: "memory");
        if (lane == 0) {
            __hip_atomic_store(&flags[(layer * 24 + t) * 128 + w * 32 + lbid], 1u,
                               __ATOMIC_RELAXED, __HIP_MEMORY_SCOPE_AGENT);
        }
    }
}

// ---- fc: register-path A, NORMAL cached loads ----
#define FC_ISSUE_G(buf, mtv, ks0)                                             \
    {                                                                         \
        _Pragma("unroll")                                                     \
        for (int u_ = 0; u_ < 4; ++u_) {                                      \
            _Pragma("unroll")                                                 \
            for (int i_ = 0; i_ < 4; ++i_) {                                  \
                int rl_ = i_ * 16 + lrow;                                     \
                int k_ = (ks0) + u_ * 32 + lk;                                \
                const unsigned short* ap_ = h2                                \
                    + (size_t)(2 * (mtv) + wm + 1) * HSLOT                    \
                    + ((k_ >> 4) << 10) + (rl_ << 4) + (k_ & 15);             \
                asm volatile("global_load_dwordx4 %0, %1, off"                \
                             : "=v"(buf[u_ * 4 + i_]) : "v"(ap_) : "memory"); \
            }                                                                 \
        }                                                                     \
    }
#define FC_MFMA_G(buf, ks0)                                                   \
    {                                                                         \
        _Pragma("unroll")                                                     \
        for (int u_ = 0; u_ < 4; ++u_) {                                      \
            int ks_ = (ks0) + u_ * 32 + lk;                                   \
            _Pragma("unroll")                                                 \
            for (int jj_ = 0; jj_ < 4; ++jj_) {                               \
                int row_ = wn * 64 + jj_ * 16 + lrow;                         \
                int gx_ = ((ks_ >> 3) ^ (row_ & 7)) << 3;                     \
                bf16x8 bq_ = *(const bf16x8*)&lB[row_ * 512 + gx_];           \
                _Pragma("unroll")                                             \
                for (int i_ = 0; i_ < 4; ++i_)                                \
                    acc[i_][jj_] = __builtin_amdgcn_mfma_f32_16x16x32_bf16(   \
                        buf[u_ * 4 + i_], bq_, acc[i_][jj_], 0, 0, 0);        \
            }                                                                 \
        }                                                                     \
    }
#define FC_STORES                                                             \
    {                                                                         \
        _Pragma("unroll")                                                     \
        for (int i_ = 0; i_ < 4; ++i_) {                                      \
            _Pragma("unroll")                                                 \
            for (int jj_ = 0; jj_ < 4; ++jj_) {                               \
                int n_ = n0 + wn * 64 + jj_ * 16 + lrow;                      \
                float bias_ = fcb[n_];                                        \
                _Pragma("unroll")                                             \
                for (int r_ = 0; r_ < 4; ++r_) {                              \
                    int m_ = m0 + wm * 64 + i_ * 16 + ((lane >> 4) << 2) + r_;\
                    int b_ = m_ & 63, t_ = m_ >> 6;                           \
                    __builtin_nontemporal_store(                              \
                        acc[i_][jj_][r_] + bias_,                             \
                        &out[(size_t)(b_ * 24 + t_) * 32000 + n_]);           \
                }                                                             \
            }                                                                 \
        }                                                                     \
    }

// ---------------- fc GEMM (250 blocks, after wavefront) ----------------
// Cross-tile pipeline: next tile's A-loads are issued BEFORE this tile's
// stores, so the tile-entry vmcnt(63) retires only the loads (stores keep
// draining in background).
__global__ __launch_bounds__(256, 1) void fc_gemm(
    const unsigned short* __restrict__ hst,
    const float* __restrict__ fcW,
    const float* __restrict__ fcb,
    float* __restrict__ out)
{
    extern __shared__ char smem[];
    unsigned short* lB = (unsigned short*)smem;    // [128][512] bf16 swizzled
    const int tid = threadIdx.x;
    const int lane = tid & 63, w = tid >> 6;
    const int lrow = lane & 15, lk = (lane >> 4) * 8;
    const int wm = w >> 1, wn = w & 1;
    const unsigned short* h2 = hst + (size_t)2 * 25 * HSLOT;
    const int n0 = blockIdx.x * 128;

    // stage fcW panel once: f32 -> bf16, XOR swizzle
    for (int idx = tid; idx < 128 * 64; idx += 256) {
        int row = idx >> 6, g = idx & 63;
        const float* bp = &fcW[(size_t)(n0 + row) * 512 + g * 8];
        f32x4 v0 = *(const f32x4*)bp;
        f32x4 v1 = *(const f32x4*)(bp + 4);
        unsigned short o[8];
        #pragma unroll
        for (int x = 0; x < 4; ++x) { o[x] = f2b(v0[x]); o[4 + x] = f2b(v1[x]); }
        *(bf16x8*)&lB[row * 512 + ((g ^ (row & 7)) << 3)] = *(bf16x8*)o;
    }
    __syncthreads();

    bf16x8 gA[16], gB[16];

    // ---- tile 0 (peeled: no stores in flight)
    {
        const int m0 = 0;
        f32x4 acc[4][4] = {};
        FC_ISSUE_G(gA, 0, 0); FC_ISSUE_G(gB, 0, 128);
        VM_WAIT(16); FC_MFMA_G(gA, 0);
        FC_ISSUE_G(gA, 0, 256);
        VM_WAIT(16); FC_MFMA_G(gB, 128);
        FC_ISSUE_G(gB, 0, 384);
        VM_WAIT(16); FC_MFMA_G(gA, 256);
        VM_WAIT(0);  FC_MFMA_G(gB, 384);
        // next tile's first 32 loads BEFORE stores
        FC_ISSUE_G(gA, 1, 0); FC_ISSUE_G(gB, 1, 128);
        FC_STORES;
    }

    for (int mt = 1; mt < 12; ++mt) {
        const int m0 = mt * 128;
        f32x4 acc[4][4] = {};
        // entry: 32 loads (oldest) + 64 stores outstanding = 96.
        // vmcnt(63) retires 33 oldest = all loads (+1 store).
        VM_WAIT(63);
        FC_MFMA_G(gA, 0);
        FC_ISSUE_G(gA, mt, 256);
        FC_MFMA_G(gB, 128);
        FC_ISSUE_G(gB, mt, 384);
        VM_WAIT(16);   // stores have drained ~2 MFMA groups by now
        FC_MFMA_G(gA, 256);
        VM_WAIT(0);
        FC_MFMA_G(gB, 384);
        if (mt < 11) { FC_ISSUE_G(gA, mt + 1, 0); FC_ISSUE_G(gB, mt + 1, 128); }
        FC_STORES;
    }
}

// ---------------- launch ----------------
extern "C" void kernel_launch(void* const* d_in, const int* in_sizes, int n_in,
                              void* d_out, int out_size, void* d_ws, size_t ws_size,
                              hipStream_t stream) {
    const float* qf  = (const float*)d_in[0];
    const float* imf = (const float*)d_in[1];
    const int*   seq = (const int*)d_in[2];
    const float* emb = (const float*)d_in[3];
    // d_in[4..6] dead code
    const float* fcW = (const float*)d_in[7];
    const float* fcb = (const float*)d_in[8];
    const float* Wih[3] = {(const float*)d_in[9],  (const float*)d_in[13], (const float*)d_in[17]};
    const float* Whh[3] = {(const float*)d_in[10], (const float*)d_in[14], (const float*)d_in[18]};
    const float* bih[3] = {(const float*)d_in[11], (const float*)d_in[15], (const float*)d_in[19]};
    const float* bhh[3] = {(const float*)d_in[12], (const float*)d_in[16], (const float*)d_in[20]};

    char* ws = (char*)d_ws;
    unsigned short* X     = (unsigned short*)(ws + 0);          // 3,932,160
    float*          G0    = (float*)(ws + 3932160);             // 12,582,912
    unsigned short* hst   = (unsigned short*)(ws + 16515072);   // 4,915,200
    unsigned int*   flags = (unsigned int*)(ws + 21430272);     // 36,864
    unsigned short* Wpk   = (unsigned short*)(ws + 21467136);   // 10,485,760

    // one prep dispatch: pack_w + build_x + zero(flags, h slot0)
    prep<<<7688, 256, 0, stream>>>(
        Whh[0], Wih[1], Whh[1], Wih[2], Whh[2], Wpk,
        qf, imf, seq, emb, X, flags, hst);

    // G0 = X @ W_ih0^T + b_ih0 + b_hh0
    gemm128<<<192, 256, 0, stream>>>(
        X, 1280, Wih[0], 1280, 1280, bih[0], bhh[0], G0, 2048, 12, 192 / 8);

    // wavefront: 96 blocks, 128 KiB dynamic LDS
    lstm_wave<<<NLSTM, 256, 131072, stream>>>(
        Wpk, G0, bih[1], bhh[1], bih[2], bhh[2], hst, flags);

    // fc: 250 blocks, 128 KiB dynamic LDS
    fc_gemm<<<NTILE_N, 256, 131072, stream>>>(
        hst, fcW, fcb, (float*)d_out);
}

// Round 16
// 295.731 us; speedup vs baseline: 1.1200x; 1.0130x over previous
//
#include <hip/hip_runtime.h>
#include <hip/hip_bf16.h>
#include <stdint.h>

// Answer_Decoder: B=64, T=24, H=512, V=32000, E=256. All I/O float32.
// Attention is dead code (softmax over size-1 axis => ctx == cat(q,img)).
// Pipeline (4 dispatches):
//   0) prep: pack_w + build_x + zero(flags, h slot0)
//   1) gemm128: G0 = X @ W_ih0^T + b_ih0 + b_hh0
//   2) lstm_wave (96 blocks): (t,layer) wavefront; W persistent in LDS;
//      h slab layout; h stores sc1 write-through; A reads normal cached.
//      SYNC: per-block flags [3][24][32]; ONLY WAVE 0 polls globally
//      (96 pollers, 1 line/dep-set) and broadcasts via LDS; waves 1-3
//      spin on LDS (no fabric traffic). Publisher = last wave via LDS cnt.
//   3) fc_gemm (250 blocks): fcW panel in LDS; cross-tile load/store
//      decoupling (vmcnt(63) entry); nt out stores.

typedef short bf16x8 __attribute__((ext_vector_type(8)));
typedef float f32x4 __attribute__((ext_vector_type(4)));

#define NLSTM 96
#define NTILE_N 250          // 32000/128
#define HSLOT 32768          // elems per (layer,t) h slot: 32 slabs * 64 * 16

__device__ __forceinline__ unsigned short f2b(float f) {
    uint32_t u = __builtin_bit_cast(uint32_t, f);
    uint32_t r = u + 0x7FFFu + ((u >> 16) & 1u);
    return (unsigned short)(r >> 16);
}
__device__ __forceinline__ float fsig(float x) {
    float e = __expf(-x);
    return __builtin_amdgcn_rcpf(1.0f + e);
}
__device__ __forceinline__ float ftanh(float x) {
    float e = __expf(-2.0f * x);
    return (1.0f - e) * __builtin_amdgcn_rcpf(1.0f + e);
}

// ---------------- prep: pack_w + build_x + zeroing, one dispatch ----------
__global__ __launch_bounds__(256) void prep(
    const float* __restrict__ Whh0,
    const float* __restrict__ Wih1, const float* __restrict__ Whh1,
    const float* __restrict__ Wih2, const float* __restrict__ Whh2,
    unsigned short* __restrict__ Wpk,
    const float* __restrict__ qf,
    const float* __restrict__ imf,
    const int* __restrict__ seq,
    const float* __restrict__ emb,
    unsigned short* __restrict__ X,
    unsigned int* __restrict__ flags,     // 2304 u32
    unsigned short* __restrict__ hst)
{
    int gid = blockIdx.x;
    int tid = threadIdx.x;
    if (gid < 6144) {
        int layer = gid / (32 * 64);
        int rem = gid % (32 * 64);
        int lbid = rem >> 6, r = rem & 63;
        int q = r >> 4, jj = r & 15;
        int grow = q * 512 + lbid * 16 + jj;
        int K = (layer == 0) ? 512 : 1024;
        size_t wbase = (layer == 0) ? 0
                     : (layer == 1) ? (size_t)32 * 64 * 512
                                    : (size_t)32 * 64 * 512 + (size_t)32 * 64 * 1024;
        unsigned short* dst = Wpk + wbase + ((size_t)lbid * 64 + r) * K;
        const float *s0, *s1 = nullptr;
        if (layer == 0)      { s0 = Whh0 + (size_t)grow * 512; }
        else if (layer == 1) { s0 = Wih1 + (size_t)grow * 512; s1 = Whh1 + (size_t)grow * 512; }
        else                 { s0 = Wih2 + (size_t)grow * 512; s1 = Whh2 + (size_t)grow * 512; }
        int half = tid >> 7, k4 = tid & 127;       // 128 threads per half
        const float* src = (half == 0) ? s0 : s1;
        if (src) {
            f32x4 v = *(const f32x4*)&src[k4 * 4];
            unsigned short o[4];
            #pragma unroll
            for (int j = 0; j < 4; ++j) o[j] = f2b(v[j]);
            *(uint64_t*)&dst[half * 512 + k4 * 4] = *(uint64_t*)o;
        }
    } else if (gid < 7680) {
        int r = gid - 6144;
        int t = r >> 6, b = r & 63;
        int tok = seq[b * 24 + t];
        for (int e = tid; e < 1280; e += 256) {
            float v;
            if (e < 256)      v = emb[(size_t)tok * 256 + e];
            else if (e < 768) v = qf[b * 512 + (e - 256)];
            else              v = imf[b * 512 + (e - 768)];
            X[(size_t)r * 1280 + e] = f2b(v);
        }
    } else {
        int z = (gid - 7680) * 256 + tid;          // 8 blocks * 256 = 2048 workers
        for (int i = z; i < 2304; i += 2048) flags[i] = 0u;
        unsigned int* h32 = (unsigned int*)hst;
        for (int l = 0; l < 3; ++l) {
            unsigned int* base = h32 + (size_t)l * 25 * (HSLOT / 2);
            for (int i = z; i < HSLOT / 2; i += 2048) base[i] = 0u;
        }
    }
}

// ---------------- 128x128 MFMA GEMM (G0): A bf16, W f32 (in-staging cvt) ----
__global__ __launch_bounds__(256) void gemm128(
    const unsigned short* __restrict__ A, int lda,
    const float* __restrict__ Wf, int ldb,
    int K,
    const float* __restrict__ bias0,
    const float* __restrict__ bias1,
    float* __restrict__ outf, int ldo, int mblocks, int xcdq)
{
    __shared__ unsigned short lA[128 * 72];
    __shared__ unsigned short lB[128 * 72];
    int lin = blockIdx.x;
    int wg = (lin & 7) * xcdq + (lin >> 3);
    const int m0 = (wg % mblocks) * 128, n0 = (wg / mblocks) * 128;
    const int tid = threadIdx.x;
    const int lane = tid & 63, wid = tid >> 6;
    const int wm = wid >> 1, wn = wid & 1;

    f32x4 acc[4][4] = {};

    for (int kt = 0; kt < K; kt += 64) {
        #pragma unroll
        for (int c = 0; c < 4; ++c) {
            int chunk = tid + c * 256;
            int row = chunk >> 3, kc = (chunk & 7) * 8;
            *(bf16x8*)&lA[row * 72 + kc] =
                *(const bf16x8*)&A[(size_t)(m0 + row) * lda + kt + kc];
            const float* bp = &Wf[(size_t)(n0 + row) * ldb + kt + kc];
            f32x4 v0 = *(const f32x4*)bp;
            f32x4 v1 = *(const f32x4*)(bp + 4);
            unsigned short o[8];
            #pragma unroll
            for (int x = 0; x < 4; ++x) { o[x] = f2b(v0[x]); o[4 + x] = f2b(v1[x]); }
            *(bf16x8*)&lB[row * 72 + kc] = *(bf16x8*)o;
        }
        __syncthreads();
        #pragma unroll
        for (int ks = 0; ks < 64; ks += 32) {
            int kl = ks + ((lane >> 4) << 3);
            bf16x8 af[4], bfr[4];
            #pragma unroll
            for (int i = 0; i < 4; ++i)
                af[i] = *(const bf16x8*)&lA[(wm * 64 + i * 16 + (lane & 15)) * 72 + kl];
            #pragma unroll
            for (int j = 0; j < 4; ++j)
                bfr[j] = *(const bf16x8*)&lB[(wn * 64 + j * 16 + (lane & 15)) * 72 + kl];
            #pragma unroll
            for (int i = 0; i < 4; ++i)
                #pragma unroll
                for (int j = 0; j < 4; ++j)
                    acc[i][j] = __builtin_amdgcn_mfma_f32_16x16x32_bf16(
                        af[i], bfr[j], acc[i][j], 0, 0, 0);
        }
        __syncthreads();
    }

    #pragma unroll
    for (int i = 0; i < 4; ++i) {
        #pragma unroll
        for (int j = 0; j < 4; ++j) {
            int n = n0 + wn * 64 + j * 16 + (lane & 15);
            float bias = bias0[n] + bias1[n];
            #pragma unroll
            for (int r = 0; r < 4; ++r) {
                int m = m0 + wm * 64 + i * 16 + ((lane >> 4) << 2) + r;
                outf[(size_t)m * ldo + n] = acc[i][j][r] + bias;
            }
        }
    }
}

// ---- lstm primitives: A reads NORMAL CACHED; h in slab layout ----
#define ISSUE_CHUNK(buf, kb0)                                                 \
    {                                                                         \
        _Pragma("unroll")                                                     \
        for (int u_ = 0; u_ < 8; ++u_) {                                      \
            int kg_ = (kb0) + u_ * 32 + lk;                                   \
            const unsigned short* hb_ = (kg_ < 512) ? A0 : A1;                \
            int kk_ = kg_ & 511;                                              \
            const unsigned short* ap_ =                                       \
                hb_ + ((kk_ >> 4) << 10) + brow16 + (kk_ & 15);               \
            asm volatile("global_load_dwordx4 %0, %1, off"                    \
                         : "=v"(buf[u_]) : "v"(ap_) : "memory");              \
        }                                                                     \
    }
#define MFMA_CHUNK(buf, kb0)                                                  \
    {                                                                         \
        _Pragma("unroll")                                                     \
        for (int u_ = 0; u_ < 8; ++u_) {                                      \
            int ksl_ = (kb0) + u_ * 32 + lk;                                  \
            _Pragma("unroll")                                                 \
            for (int q_ = 0; q_ < 4; ++q_) {                                  \
                int gx_ = ((ksl_ >> 3) ^ (lrow & 7)) << 3;                    \
                bf16x8 bq_ = *(const bf16x8*)&lb[(q_ * 16 + lrow) * K + gx_]; \
                acc[q_] = __builtin_amdgcn_mfma_f32_16x16x32_bf16(            \
                    buf[u_], bq_, acc[q_], 0, 0, 0);                          \
            }                                                                 \
        }                                                                     \
    }
#define VM_WAIT(n) { asm volatile("s_waitcnt vmcnt(" #n ")" ::: "memory");    \
                     __builtin_amdgcn_sched_barrier(0); }
// wave-0 global poll of one 32-word per-block flag set (1 cache line)
#define POLL32(fbase)                                                         \
    {                                                                         \
        const unsigned int* fp_ = (fbase);                                    \
        int idx_ = lane & 31;                                                 \
        while (true) {                                                        \
            unsigned v_ = __hip_atomic_load((unsigned int*)&fp_[idx_],        \
                                            __ATOMIC_RELAXED,                 \
                                            __HIP_MEMORY_SCOPE_AGENT);       \
            if (__all(v_ != 0u)) break;                                       \
            __builtin_amdgcn_s_sleep(1);                                      \
        }                                                                     \
    }
// LDS spin for waves 1-3 (no fabric traffic)
#define LDS_SPIN(ptr)                                                         \
    {                                                                         \
        while (__hip_atomic_load((ptr), __ATOMIC_RELAXED,                     \
                                 __HIP_MEMORY_SCOPE_WORKGROUP) == 0u)         \
            __builtin_amdgcn_s_sleep(1);                                      \
    }

// ---------------- persistent wavefront LSTM (96 blocks) ----------------
// flags layout: [3][24][32 blocks] u32 (per-block, single-writer)
__global__ __launch_bounds__(256, 1) void lstm_wave(
    const unsigned short* __restrict__ Wpk,
    const float* __restrict__ G0,            // [24][64][2048]
    const float* __restrict__ bih1, const float* __restrict__ bhh1,
    const float* __restrict__ bih2, const float* __restrict__ bhh2,
    unsigned short* __restrict__ hst,        // [3][25][HSLOT] slab layout
    unsigned int* __restrict__ flags)        // [3][24][32]
{
    extern __shared__ char smem[];
    __shared__ unsigned int syncA[24];   // own-layer dep observed
    __shared__ unsigned int syncB[24];   // lower-layer dep observed
    __shared__ unsigned int lcnt[24];    // waves finished this t
    unsigned short* lb = (unsigned short*)smem;   // [64][K], XOR-swizzled
    const int bid = blockIdx.x;
    const int tid = threadIdx.x;
    const int lane = tid & 63, w = tid >> 6;
    const int lrow = lane & 15, lk = (lane >> 4) * 8;
    const int layer = bid >> 5;
    const int lbid = bid & 31;
    const int j0 = lbid * 16;

    const int K = (layer == 0) ? 512 : 1024;
    const size_t wbase = (layer == 0) ? 0
                       : (layer == 1) ? (size_t)32 * 64 * 512
                                      : (size_t)32 * 64 * 512 + (size_t)32 * 64 * 1024;
    const unsigned short* Wblk = Wpk + wbase + (size_t)lbid * 64 * K;

    if (tid < 24) { syncA[tid] = 0u; syncB[tid] = 0u; lcnt[tid] = 0u; }
    {   // stage W once, granule-XOR swizzle
        const int kshift = (layer == 0) ? 6 : 7;
        const int gm = (K >> 3) - 1;
        const int total = 64 << kshift;
        for (int idx = tid; idx < total; idx += 256) {
            int row = idx >> kshift, g = idx & gm;
            int gx = g ^ (row & 7);
            *(bf16x8*)&lb[row * K + gx * 8] =
                *(const bf16x8*)&Wblk[(size_t)row * K + g * 8];
        }
    }
    __syncthreads();   // the only block barrier

    unsigned short* hl = hst + (size_t)layer * 25 * HSLOT;
    const unsigned short* hlow =
        (layer > 0) ? hst + (size_t)(layer - 1) * 25 * HSLOT : nullptr;

    float pb[4] = {0.f, 0.f, 0.f, 0.f};
    if (layer == 1) {
        #pragma unroll
        for (int q = 0; q < 4; ++q)
            pb[q] = bih1[q * 512 + j0 + lrow] + bhh1[q * 512 + j0 + lrow];
    } else if (layer == 2) {
        #pragma unroll
        for (int q = 0; q < 4; ++q)
            pb[q] = bih2[q * 512 + j0 + lrow] + bhh2[q * 512 + j0 + lrow];
    }

    float creg[4] = {0.f, 0.f, 0.f, 0.f};
    const int brow16 = (w * 16 + lrow) << 4;

    for (int t = 0; t < 24; ++t) {
        // G0 prefetch (static, overlaps polls)
        float g0p[16];
        if (layer == 0) {
            const float* gp = G0 + (size_t)t * 64 * 2048;
            #pragma unroll
            for (int r = 0; r < 4; ++r) {
                int b = w * 16 + ((lane >> 4) << 2) + r;
                #pragma unroll
                for (int q = 0; q < 4; ++q)
                    g0p[r * 4 + q] = gp[(size_t)b * 2048 + q * 512 + j0 + lrow];
            }
        }

        const unsigned short* A0 = (layer == 0)
            ? hl + (size_t)t * HSLOT
            : hlow + (size_t)(t + 1) * HSLOT;
        const unsigned short* A1 = (layer == 0)
            ? A0
            : hl + (size_t)t * HSLOT;

        f32x4 acc[4] = {};
        bf16x8 bufA[8], bufB[8], bufC[8], bufD[8];

        if (layer == 0) {
            if (t > 0) {
                if (w == 0) {
                    POLL32(flags + (t - 1) * 32);
                    if (lane == 0)
                        __hip_atomic_store(&syncA[t], 1u, __ATOMIC_RELAXED,
                                           __HIP_MEMORY_SCOPE_WORKGROUP);
                } else {
                    LDS_SPIN(&syncA[t]);
                }
            }
            ISSUE_CHUNK(bufA, 0); ISSUE_CHUNK(bufB, 256);
            VM_WAIT(8); MFMA_CHUNK(bufA, 0);
            VM_WAIT(0); MFMA_CHUNK(bufB, 256);
        } else {
            // dep 1: own-layer t-1 (A1 rows) -> issue C/D early
            if (t > 0) {
                if (w == 0) {
                    POLL32(flags + (layer * 24 + t - 1) * 32);
                    if (lane == 0)
                        __hip_atomic_store(&syncA[t], 1u, __ATOMIC_RELAXED,
                                           __HIP_MEMORY_SCOPE_WORKGROUP);
                } else {
                    LDS_SPIN(&syncA[t]);
                }
            }
            ISSUE_CHUNK(bufC, 512); ISSUE_CHUNK(bufD, 768);
            // dep 2: lower layer t (A0 rows)
            if (w == 0) {
                POLL32(flags + ((layer - 1) * 24 + t) * 32);
                if (lane == 0)
                    __hip_atomic_store(&syncB[t], 1u, __ATOMIC_RELAXED,
                                       __HIP_MEMORY_SCOPE_WORKGROUP);
            } else {
                LDS_SPIN(&syncB[t]);
            }
            ISSUE_CHUNK(bufA, 0); ISSUE_CHUNK(bufB, 256);
            VM_WAIT(24); MFMA_CHUNK(bufC, 512);
            VM_WAIT(16); MFMA_CHUNK(bufD, 768);
            VM_WAIT(8);  MFMA_CHUNK(bufA, 0);
            VM_WAIT(0);  MFMA_CHUNK(bufB, 256);
        }

        // epilogue; h stores: full-line slab writes, sc1 write-through
        unsigned short* hslot = hl + (size_t)(t + 1) * HSLOT + (lbid << 10);
        #pragma unroll
        for (int r = 0; r < 4; ++r) {
            int b = w * 16 + ((lane >> 4) << 2) + r;
            float g[4];
            #pragma unroll
            for (int q = 0; q < 4; ++q) {
                float p = (layer == 0) ? g0p[r * 4 + q] : pb[q];
                g[q] = acc[q][r] + p;
            }
            float ig = fsig(g[0]);
            float fg = fsig(g[1]);
            float gg = ftanh(g[2]);
            float og = fsig(g[3]);
            float cn = fg * creg[r] + ig * gg;
            creg[r] = cn;
            float h = og * ftanh(cn);
            unsigned int hb = (unsigned int)f2b(h);
            unsigned short* hp = hslot + (b << 4) + lrow;
            asm volatile("global_store_short %0, %1, off sc1"
                         :: "v"(hp), "v"(hb) : "memory");
        }
        asm volatile("s_waitcnt vmcnt(0)" ::: "memory");
        // last-finishing wave publishes the per-block flag
        if (lane == 0) {
            unsigned old = __hip_atomic_fetch_add(&lcnt[t], 1u, __ATOMIC_RELAXED,
                                                  __HIP_MEMORY_SCOPE_WORKGROUP);
            if (old == 3u)
                __hip_atomic_store(&flags[(layer * 24 + t) * 32 + lbid], 1u,
                                   __ATOMIC_RELAXED, __HIP_MEMORY_SCOPE_AGENT);
        }
    }
}

// ---- fc: register-path A, NORMAL cached loads ----
#define FC_ISSUE_G(buf, mtv, ks0)                                             \
    {                                                                         \
        _Pragma("unroll")                                                     \
        for (int u_ = 0; u_ < 4; ++u_) {                                      \
            _Pragma("unroll")                                                 \
            for (int i_ = 0; i_ < 4; ++i_) {                                  \
                int rl_ = i_ * 16 + lrow;                                     \
                int k_ = (ks0) + u_ * 32 + lk;                                \
                const unsigned short* ap_ = h2                                \
                    + (size_t)(2 * (mtv) + wm + 1) * HSLOT                    \
                    + ((k_ >> 4) << 10) + (rl_ << 4) + (k_ & 15);             \
                asm volatile("global_load_dwordx4 %0, %1, off"                \
                             : "=v"(buf[u_ * 4 + i_]) : "v"(ap_) : "memory"); \
            }                                                                 \
        }                                                                     \
    }
#define FC_MFMA_G(buf, ks0)                                                   \
    {                                                                         \
        _Pragma("unroll")                                                     \
        for (int u_ = 0; u_ < 4; ++u_) {                                      \
            int ks_ = (ks0) + u_ * 32 + lk;                                   \
            _Pragma("unroll")                                                 \
            for (int jj_ = 0; jj_ < 4; ++jj_) {                               \
                int row_ = wn * 64 + jj_ * 16 + lrow;                         \
                int gx_ = ((ks_ >> 3) ^ (row_ & 7)) << 3;                     \
                bf16x8 bq_ = *(const bf16x8*)&lB[row_ * 512 + gx_];           \
                _Pragma("unroll")                                             \
                for (int i_ = 0; i_ < 4; ++i_)                                \
                    acc[i_][jj_] = __builtin_amdgcn_mfma_f32_16x16x32_bf16(   \
                        buf[u_ * 4 + i_], bq_, acc[i_][jj_], 0, 0, 0);        \
            }                                                                 \
        }                                                                     \
    }
#define FC_STORES                                                             \
    {                                                                         \
        _Pragma("unroll")                                                     \
        for (int i_ = 0; i_ < 4; ++i_) {                                      \
            _Pragma("unroll")                                                 \
            for (int jj_ = 0; jj_ < 4; ++jj_) {                               \
                int n_ = n0 + wn * 64 + jj_ * 16 + lrow;                      \
                float bias_ = fcb[n_];                                        \
                _Pragma("unroll")                                             \
                for (int r_ = 0; r_ < 4; ++r_) {                              \
                    int m_ = m0 + wm * 64 + i_ * 16 + ((lane >> 4) << 2) + r_;\
                    int b_ = m_ & 63, t_ = m_ >> 6;                           \
                    __builtin_nontemporal_store(                              \
                        acc[i_][jj_][r_] + bias_,                             \
                        &out[(size_t)(b_ * 24 + t_) * 32000 + n_]);           \
                }                                                             \
            }                                                                 \
        }                                                                     \
    }

// ---------------- fc GEMM (250 blocks, after wavefront) ----------------
__global__ __launch_bounds__(256, 1) void fc_gemm(
    const unsigned short* __restrict__ hst,
    const float* __restrict__ fcW,
    const float* __restrict__ fcb,
    float* __restrict__ out)
{
    extern __shared__ char smem[];
    unsigned short* lB = (unsigned short*)smem;    // [128][512] bf16 swizzled
    const int tid = threadIdx.x;
    const int lane = tid & 63, w = tid >> 6;
    const int lrow = lane & 15, lk = (lane >> 4) * 8;
    const int wm = w >> 1, wn = w & 1;
    const unsigned short* h2 = hst + (size_t)2 * 25 * HSLOT;
    const int n0 = blockIdx.x * 128;

    // stage fcW panel once: f32 -> bf16, XOR swizzle
    for (int idx = tid; idx < 128 * 64; idx += 256) {
        int row = idx >> 6, g = idx & 63;
        const float* bp = &fcW[(size_t)(n0 + row) * 512 + g * 8];
        f32x4 v0 = *(const f32x4*)bp;
        f32x4 v1 = *(const f32x4*)(bp + 4);
        unsigned short o[8];
        #pragma unroll
        for (int x = 0; x < 4; ++x) { o[x] = f2b(v0[x]); o[4 + x] = f2b(v1[x]); }
        *(bf16x8*)&lB[row * 512 + ((g ^ (row & 7)) << 3)] = *(bf16x8*)o;
    }
    __syncthreads();

    bf16x8 gA[16], gB[16];

    // ---- tile 0 (peeled: no stores in flight)
    {
        const int m0 = 0;
        f32x4 acc[4][4] = {};
        FC_ISSUE_G(gA, 0, 0); FC_ISSUE_G(gB, 0, 128);
        VM_WAIT(16); FC_MFMA_G(gA, 0);
        FC_ISSUE_G(gA, 0, 256);
        VM_WAIT(16); FC_MFMA_G(gB, 128);
        FC_ISSUE_G(gB, 0, 384);
        VM_WAIT(16); FC_MFMA_G(gA, 256);
        VM_WAIT(0);  FC_MFMA_G(gB, 384);
        FC_ISSUE_G(gA, 1, 0); FC_ISSUE_G(gB, 1, 128);
        FC_STORES;
    }

    for (int mt = 1; mt < 12; ++mt) {
        const int m0 = mt * 128;
        f32x4 acc[4][4] = {};
        // entry: 32 loads (oldest) + 64 stores outstanding = 96.
        // vmcnt(63) retires 33 oldest = all loads (+1 store).
        VM_WAIT(63);
        FC_MFMA_G(gA, 0);
        FC_ISSUE_G(gA, mt, 256);
        FC_MFMA_G(gB, 128);
        FC_ISSUE_G(gB, mt, 384);
        VM_WAIT(16);
        FC_MFMA_G(gA, 256);
        VM_WAIT(0);
        FC_MFMA_G(gB, 384);
        if (mt < 11) { FC_ISSUE_G(gA, mt + 1, 0); FC_ISSUE_G(gB, mt + 1, 128); }
        FC_STORES;
    }
}

// ---------------- launch ----------------
extern "C" void kernel_launch(void* const* d_in, const int* in_sizes, int n_in,
                              void* d_out, int out_size, void* d_ws, size_t ws_size,
                              hipStream_t stream) {
    const float* qf  = (const float*)d_in[0];
    const float* imf = (const float*)d_in[1];
    const int*   seq = (const int*)d_in[2];
    const float* emb = (const float*)d_in[3];
    // d_in[4..6] dead code
    const float* fcW = (const float*)d_in[7];
    const float* fcb = (const float*)d_in[8];
    const float* Wih[3] = {(const float*)d_in[9],  (const float*)d_in[13], (const float*)d_in[17]};
    const float* Whh[3] = {(const float*)d_in[10], (const float*)d_in[14], (const float*)d_in[18]};
    const float* bih[3] = {(const float*)d_in[11], (const float*)d_in[15], (const float*)d_in[19]};
    const float* bhh[3] = {(const float*)d_in[12], (const float*)d_in[16], (const float*)d_in[20]};

    char* ws = (char*)d_ws;
    unsigned short* X     = (unsigned short*)(ws + 0);          // 3,932,160
    float*          G0    = (float*)(ws + 3932160);             // 12,582,912
    unsigned short* hst   = (unsigned short*)(ws + 16515072);   // 4,915,200
    unsigned int*   flags = (unsigned int*)(ws + 21430272);     // 9,216
    unsigned short* Wpk   = (unsigned short*)(ws + 21467136);   // 10,485,760

    // one prep dispatch: pack_w + build_x + zero(flags, h slot0)
    prep<<<7688, 256, 0, stream>>>(
        Whh[0], Wih[1], Whh[1], Wih[2], Whh[2], Wpk,
        qf, imf, seq, emb, X, flags, hst);

    // G0 = X @ W_ih0^T + b_ih0 + b_hh0
    gemm128<<<192, 256, 0, stream>>>(
        X, 1280, Wih[0], 1280, 1280, bih[0], bhh[0], G0, 2048, 12, 192 / 8);

    // wavefront: 96 blocks, 128 KiB dynamic LDS
    lstm_wave<<<NLSTM, 256, 131072, stream>>>(
        Wpk, G0, bih[1], bhh[1], bih[2], bhh[2], hst, flags);

    // fc: 250 blocks, 128 KiB dynamic LDS
    fc_gemm<<<NTILE_N, 256, 131072, stream>>>(
        hst, fcW, fcb, (float*)d_out);
}